// Round 1
// baseline (301.225 us; speedup 1.0000x reference)
//
#include <hip/hip_runtime.h>

#define DIM 768
#define NB  32
#define LQ  512
#define NV  128

typedef unsigned short u16;
typedef unsigned int   u32;
typedef __bf16 bf16x8 __attribute__((ext_vector_type(8)));
typedef float  f32x4  __attribute__((ext_vector_type(4)));
typedef u16    u16x8  __attribute__((ext_vector_type(8)));
typedef u16    u16x4  __attribute__((ext_vector_type(4)));

__device__ __forceinline__ u16 f2bf(float f) {
    u32 u = __float_as_uint(f);
    return (u16)((u + 0x7FFFu + ((u >> 16) & 1u)) >> 16);   // RNE
}

__device__ __forceinline__ bf16x8 ld_frag(const u16* p) {
    return __builtin_bit_cast(bf16x8, *(const u16x8*)p);
}

// ---------------------------------------------------------------------------
// Kernel 0: videos (b,v,d) fp32 -> Vt (b,d,v) bf16  (B-operand layout for PV)
// ---------------------------------------------------------------------------
__global__ __launch_bounds__(256) void vt_kernel(const float* __restrict__ videos,
                                                 u16* __restrict__ vt) {
    const int b  = blockIdx.y;
    const int d0 = blockIdx.x * 64;
    const int t  = threadIdx.x;
    __shared__ u16 T[64][136];                      // [d_local][v], pad 8
    const float* src = videos + (size_t)b * NV * DIM;
#pragma unroll
    for (int p = 0; p < 8; ++p) {                   // 128 v x 64 d floats
        int f  = t + p * 256;
        int v  = f >> 4;                            // 0..127
        int c4 = f & 15;                            // 16 float4 per 64-float row
        float4 x = *(const float4*)(src + (size_t)v * DIM + d0 + c4 * 4);
        T[c4 * 4 + 0][v] = f2bf(x.x);
        T[c4 * 4 + 1][v] = f2bf(x.y);
        T[c4 * 4 + 2][v] = f2bf(x.z);
        T[c4 * 4 + 3][v] = f2bf(x.w);
    }
    __syncthreads();
    u16* dst = vt + ((size_t)b * DIM + d0) * NV;
#pragma unroll
    for (int p = 0; p < 4; ++p) {                   // 64 rows x 128 u16
        int f  = t + p * 256;
        int dl = f >> 4;                            // 0..63
        int v8 = f & 15;                            // 16 x u16x8 per row
        *(u16x8*)(dst + (size_t)dl * NV + v8 * 8) = *(const u16x8*)&T[dl][v8 * 8];
    }
}

// ---------------------------------------------------------------------------
// Kernel 1: C[M x 768] bf16 = A[M x 768] fp32 @ W[768 x 768]^T fp32
// 128x128 tile, BK=64, 4 waves, 16x16x32 bf16 MFMA, inline f32->bf16 staging
// ---------------------------------------------------------------------------
__global__ __launch_bounds__(256) void proj_kernel(const float* __restrict__ A,
                                                   const float* __restrict__ W,
                                                   u16* __restrict__ C) {
    __shared__ u16 sA[128][72];                     // [m][k], pad 8
    __shared__ u16 sB[128][72];                     // [n][k], pad 8
    const int t    = threadIdx.x;
    const int m0   = blockIdx.y * 128;
    const int n0   = blockIdx.x * 128;
    const int w    = t >> 6;
    const int lane = t & 63;
    const int quad = lane >> 4;
    const int ln   = lane & 15;
    const int wr   = (w >> 1) * 64;
    const int wc   = (w & 1) * 64;

    f32x4 acc[4][4] = {};
    for (int ks = 0; ks < DIM / 64; ++ks) {
        __syncthreads();
#pragma unroll
        for (int p = 0; p < 8; ++p) {               // 128 rows x 64 floats each mat
            int f   = t + p * 256;
            int row = f >> 4;
            int c4  = f & 15;
            float4 xa = *(const float4*)(A + (size_t)(m0 + row) * DIM + ks * 64 + c4 * 4);
            float4 xb = *(const float4*)(W + (size_t)(n0 + row) * DIM + ks * 64 + c4 * 4);
            u16x4 ua = { f2bf(xa.x), f2bf(xa.y), f2bf(xa.z), f2bf(xa.w) };
            u16x4 ub = { f2bf(xb.x), f2bf(xb.y), f2bf(xb.z), f2bf(xb.w) };
            *(u16x4*)&sA[row][c4 * 4] = ua;
            *(u16x4*)&sB[row][c4 * 4] = ub;
        }
        __syncthreads();
#pragma unroll
        for (int kk = 0; kk < 2; ++kk) {
            bf16x8 af[4], bfr[4];
#pragma unroll
            for (int i = 0; i < 4; ++i) af[i]  = ld_frag(&sA[wr + i * 16 + ln][kk * 32 + quad * 8]);
#pragma unroll
            for (int j = 0; j < 4; ++j) bfr[j] = ld_frag(&sB[wc + j * 16 + ln][kk * 32 + quad * 8]);
#pragma unroll
            for (int i = 0; i < 4; ++i)
#pragma unroll
                for (int j = 0; j < 4; ++j)
                    acc[i][j] = __builtin_amdgcn_mfma_f32_16x16x32_bf16(af[i], bfr[j], acc[i][j], 0, 0, 0);
        }
    }
#pragma unroll
    for (int i = 0; i < 4; ++i)
#pragma unroll
        for (int j = 0; j < 4; ++j)
#pragma unroll
            for (int r = 0; r < 4; ++r) {
                int row = m0 + wr + i * 16 + quad * 4 + r;   // C/D: row = quad*4+reg
                int col = n0 + wc + j * 16 + ln;             //      col = lane&15
                C[(size_t)row * DIM + col] = f2bf(acc[i][j][r]);
            }
}

// ---------------------------------------------------------------------------
// Kernel 2: per (b, 64-row l-tile): S = Q K^T * scale -> softmax(mask) -> P V
// ---------------------------------------------------------------------------
__global__ __launch_bounds__(256) void attn_kernel(const u16* __restrict__ Q,
                                                   const u16* __restrict__ K,
                                                   const u16* __restrict__ Vt,
                                                   const int* __restrict__ mask,
                                                   float* __restrict__ out) {
    const int b    = blockIdx.y;
    const int l0   = blockIdx.x * 64;
    const int t    = threadIdx.x;
    const int w    = t >> 6;
    const int lane = t & 63;
    const int quad = lane >> 4;
    const int ln   = lane & 15;

    __shared__ union {
        struct { u16 q[64][72]; u16 k[128][72]; } st;   // phase-1 staging (27.6 KB)
        float s[64][132];                               // scores fp32 (33.8 KB)
        u16   v[64][136];                               // phase-3 V tile (17.4 KB)
    } uS;
    __shared__ u16   sP[64][136];                       // probs bf16, A-operand layout
    __shared__ float sBias[128];

    const u16* Qb = Q + ((size_t)b * LQ + l0) * DIM;
    const u16* Kb = K + (size_t)b * NV * DIM;

    if (t < NV) sBias[t] = mask[b * NV + t] ? 0.0f : -1e9f;

    // ---- Phase 1: S(64x128) = Q_tile @ K_b^T ----
    f32x4 accS[4][2] = {};
    for (int ks = 0; ks < DIM / 64; ++ks) {
        __syncthreads();
#pragma unroll
        for (int p = 0; p < 2; ++p) {                   // Q chunk: 64 x 64 bf16
            int f = t + p * 256;
            int row = f >> 3, c8 = f & 7;
            *(u16x8*)&uS.st.q[row][c8 * 8] = *(const u16x8*)(Qb + (size_t)row * DIM + ks * 64 + c8 * 8);
        }
#pragma unroll
        for (int p = 0; p < 4; ++p) {                   // K chunk: 128 x 64 bf16
            int f = t + p * 256;
            int row = f >> 3, c8 = f & 7;
            *(u16x8*)&uS.st.k[row][c8 * 8] = *(const u16x8*)(Kb + (size_t)row * DIM + ks * 64 + c8 * 8);
        }
        __syncthreads();
#pragma unroll
        for (int kk = 0; kk < 2; ++kk) {
            bf16x8 af[4], bfr[2];
#pragma unroll
            for (int i = 0; i < 4; ++i) af[i]  = ld_frag(&uS.st.q[i * 16 + ln][kk * 32 + quad * 8]);
#pragma unroll
            for (int j = 0; j < 2; ++j) bfr[j] = ld_frag(&uS.st.k[w * 32 + j * 16 + ln][kk * 32 + quad * 8]);
#pragma unroll
            for (int i = 0; i < 4; ++i)
#pragma unroll
                for (int j = 0; j < 2; ++j)
                    accS[i][j] = __builtin_amdgcn_mfma_f32_16x16x32_bf16(af[i], bfr[j], accS[i][j], 0, 0, 0);
        }
    }
    __syncthreads();                                    // staging dead; uS.s aliases it
    const float scale = 0.03608439182435161f;           // 768^-0.5
#pragma unroll
    for (int i = 0; i < 4; ++i)
#pragma unroll
        for (int j = 0; j < 2; ++j)
#pragma unroll
            for (int r = 0; r < 4; ++r)
                uS.s[i * 16 + quad * 4 + r][w * 32 + j * 16 + ln] = accS[i][j][r] * scale;
    __syncthreads();

    // ---- Phase 2: masked softmax over v, write P bf16 ----
    {
        const int row = t >> 2, seg = t & 3;            // 4 lanes per row (same wave)
        float vals[32];
        float mx = -3.0e38f;
#pragma unroll
        for (int c = 0; c < 8; ++c) {
            float4 x  = *(const float4*)&uS.s[row][seg * 32 + c * 4];
            float4 bz = *(const float4*)&sBias[seg * 32 + c * 4];
            float a0 = x.x + bz.x, a1 = x.y + bz.y, a2 = x.z + bz.z, a3 = x.w + bz.w;
            vals[c * 4 + 0] = a0; vals[c * 4 + 1] = a1;
            vals[c * 4 + 2] = a2; vals[c * 4 + 3] = a3;
            mx = fmaxf(mx, fmaxf(fmaxf(a0, a1), fmaxf(a2, a3)));
        }
        mx = fmaxf(mx, __shfl_xor(mx, 1));
        mx = fmaxf(mx, __shfl_xor(mx, 2));
        float sum = 0.0f;
#pragma unroll
        for (int c = 0; c < 32; ++c) { float e = __expf(vals[c] - mx); vals[c] = e; sum += e; }
        sum += __shfl_xor(sum, 1);
        sum += __shfl_xor(sum, 2);
        const float inv = 1.0f / sum;
        __syncthreads();                                // all uS.s reads done before reuse
#pragma unroll
        for (int c = 0; c < 4; ++c) {
            u16x8 pk;
#pragma unroll
            for (int e = 0; e < 8; ++e) pk[e] = f2bf(vals[c * 8 + e] * inv);
            *(u16x8*)&sP[row][seg * 32 + c * 8] = pk;
        }
    }
    __syncthreads();

    // ---- Phase 3: out(64x768) = P(64x128) @ V_b(128x768), 12 N-tiles of 64 ----
    const u16* Vb = Vt + (size_t)b * DIM * NV;
    float*     Ob = out + ((size_t)b * LQ + l0) * DIM;
    for (int nt = 0; nt < 12; ++nt) {
        __syncthreads();                                // prior uS.v reads done
#pragma unroll
        for (int p = 0; p < 4; ++p) {                   // V tile: 64 d-rows x 128 v
            int f = t + p * 256;
            int dl = f >> 4, v8 = f & 15;
            *(u16x8*)&uS.v[dl][v8 * 8] = *(const u16x8*)(Vb + (size_t)(nt * 64 + dl) * NV + v8 * 8);
        }
        __syncthreads();
        f32x4 accO[4] = {};
#pragma unroll
        for (int ks = 0; ks < 4; ++ks) {                // K-dim 128 = 4 x 32
            bf16x8 af[4];
#pragma unroll
            for (int i = 0; i < 4; ++i) af[i] = ld_frag(&sP[i * 16 + ln][ks * 32 + quad * 8]);
            bf16x8 bv = ld_frag(&uS.v[w * 16 + ln][ks * 32 + quad * 8]);
#pragma unroll
            for (int i = 0; i < 4; ++i)
                accO[i] = __builtin_amdgcn_mfma_f32_16x16x32_bf16(af[i], bv, accO[i], 0, 0, 0);
        }
#pragma unroll
        for (int i = 0; i < 4; ++i)
#pragma unroll
            for (int r = 0; r < 4; ++r)
                Ob[(size_t)(i * 16 + quad * 4 + r) * DIM + nt * 64 + w * 16 + ln] = accO[i][r];
    }
}

// ---------------------------------------------------------------------------
extern "C" void kernel_launch(void* const* d_in, const int* in_sizes, int n_in,
                              void* d_out, int out_size, void* d_ws, size_t ws_size,
                              hipStream_t stream) {
    const float* lines  = (const float*)d_in[0];
    const float* videos = (const float*)d_in[1];
    const int*   mask   = (const int*)d_in[2];
    const float* w_q    = (const float*)d_in[3];
    const float* w_k    = (const float*)d_in[4];
    float*       out    = (float*)d_out;

    u16* qw = (u16*)d_ws;                        // 16384 x 768 bf16 (25.2 MB)
    u16* kw = qw + (size_t)NB * LQ * DIM;        //  4096 x 768 bf16 ( 6.3 MB)
    u16* vt = kw + (size_t)NB * NV * DIM;        // 32 x 768 x 128 bf16 (6.3 MB)

    vt_kernel  <<<dim3(DIM / 64, NB),      256, 0, stream>>>(videos, vt);
    proj_kernel<<<dim3(DIM / 128, (NB * LQ) / 128), 256, 0, stream>>>(lines,  w_q, qw);
    proj_kernel<<<dim3(DIM / 128, (NB * NV) / 128), 256, 0, stream>>>(videos, w_k, kw);
    attn_kernel<<<dim3(LQ / 64, NB),       256, 0, stream>>>(qw, kw, vt, mask, out);
}

// Round 2
// 216.322 us; speedup vs baseline: 1.3925x; 1.3925x over previous
//
#include <hip/hip_runtime.h>

#define DIM 768
#define NB  32
#define LQ  512
#define NV  128

typedef unsigned short u16;
typedef unsigned int   u32;
typedef __bf16 bf16x8 __attribute__((ext_vector_type(8)));
typedef float  f32x4  __attribute__((ext_vector_type(4)));
typedef u16    u16x8  __attribute__((ext_vector_type(8)));
typedef u16    u16x4  __attribute__((ext_vector_type(4)));

typedef __attribute__((address_space(1))) const void gvoid;
typedef __attribute__((address_space(3))) void       svoid;

__device__ __forceinline__ u16 f2bf(float f) {
    u32 u = __float_as_uint(f);
    return (u16)((u + 0x7FFFu + ((u >> 16) & 1u)) >> 16);   // RNE
}

__device__ __forceinline__ bf16x8 ld_frag(const u16* p) {
    return __builtin_bit_cast(bf16x8, *(const u16x8*)p);
}

// async global->LDS, 16B/lane. LDS dest = wave-uniform base + lane*16.
__device__ __forceinline__ void gld16(const void* g, void* l) {
    __builtin_amdgcn_global_load_lds((gvoid*)g, (svoid*)l, 16, 0, 0);
}

// ---------------------------------------------------------------------------
// fp32 -> bf16 streaming convert, 8 elems/thread (32B read, 16B write)
// ---------------------------------------------------------------------------
__global__ __launch_bounds__(256) void cvt_kernel(const float* __restrict__ src,
                                                  u16* __restrict__ dst) {
    size_t i = (size_t)blockIdx.x * 256 + threadIdx.x;
    float4 a = ((const float4*)src)[i * 2];
    float4 b = ((const float4*)src)[i * 2 + 1];
    u16x8 o = { f2bf(a.x), f2bf(a.y), f2bf(a.z), f2bf(a.w),
                f2bf(b.x), f2bf(b.y), f2bf(b.z), f2bf(b.w) };
    ((u16x8*)dst)[i] = o;
}

// ---------------------------------------------------------------------------
// videos (b,v,d) fp32 -> Vt (b,d,v) bf16  (B-operand layout for PV)
// ---------------------------------------------------------------------------
__global__ __launch_bounds__(256) void vt_kernel(const float* __restrict__ videos,
                                                 u16* __restrict__ vt) {
    const int b  = blockIdx.y;
    const int d0 = blockIdx.x * 64;
    const int t  = threadIdx.x;
    __shared__ u16 T[64][136];
    const float* src = videos + (size_t)b * NV * DIM;
#pragma unroll
    for (int p = 0; p < 8; ++p) {
        int f  = t + p * 256;
        int v  = f >> 4;
        int c4 = f & 15;
        float4 x = *(const float4*)(src + (size_t)v * DIM + d0 + c4 * 4);
        T[c4 * 4 + 0][v] = f2bf(x.x);
        T[c4 * 4 + 1][v] = f2bf(x.y);
        T[c4 * 4 + 2][v] = f2bf(x.z);
        T[c4 * 4 + 3][v] = f2bf(x.w);
    }
    __syncthreads();
    u16* dst = vt + ((size_t)b * DIM + d0) * NV;
#pragma unroll
    for (int p = 0; p < 4; ++p) {
        int f  = t + p * 256;
        int dl = f >> 4;
        int v8 = f & 15;
        *(u16x8*)(dst + (size_t)dl * NV + v8 * 8) = *(const u16x8*)&T[dl][v8 * 8];
    }
}

// ---------------------------------------------------------------------------
// C[M x 768] bf16 = A[M x 768] bf16 @ W[768 x 768]^T bf16
// m97 structure: 128x128 tile, BK=64, global_load_lds dwordx4 staging
// ---------------------------------------------------------------------------
__global__ __launch_bounds__(256) void proj_kernel(const u16* __restrict__ A,
                                                   const u16* __restrict__ W,
                                                   u16* __restrict__ C) {
    __shared__ u16 sA[128][64];                     // unpadded: global_load_lds layout
    __shared__ u16 sB[128][64];
    const int t    = threadIdx.x;
    const int m0   = blockIdx.y * 128;
    const int n0   = blockIdx.x * 128;
    const int w    = t >> 6;
    const int lane = t & 63;
    const int quad = lane >> 4;
    const int ln   = lane & 15;
    const int wr   = (w >> 1) * 64;
    const int wc   = (w & 1) * 64;
    const int srow = lane >> 3;                     // staging row within 8-row chunk
    const int scol = (lane & 7) * 8;                // staging col (u16)

    f32x4 acc[4][4] = {};
    for (int ks = 0; ks < DIM / 64; ++ks) {
        __syncthreads();                            // frag reads of prev iter done
#pragma unroll
        for (int p = 0; p < 4; ++p) {
            int r = w * 32 + p * 8;
            gld16(A + (size_t)(m0 + r + srow) * DIM + ks * 64 + scol, &sA[r][0]);
        }
#pragma unroll
        for (int p = 0; p < 4; ++p) {
            int r = w * 32 + p * 8;
            gld16(W + (size_t)(n0 + r + srow) * DIM + ks * 64 + scol, &sB[r][0]);
        }
        __syncthreads();                            // drains vmcnt
#pragma unroll
        for (int kk = 0; kk < 2; ++kk) {
            bf16x8 af[4], bfr[4];
#pragma unroll
            for (int i = 0; i < 4; ++i) af[i]  = ld_frag(&sA[wr + i * 16 + ln][kk * 32 + quad * 8]);
#pragma unroll
            for (int j = 0; j < 4; ++j) bfr[j] = ld_frag(&sB[wc + j * 16 + ln][kk * 32 + quad * 8]);
#pragma unroll
            for (int i = 0; i < 4; ++i)
#pragma unroll
                for (int j = 0; j < 4; ++j)
                    acc[i][j] = __builtin_amdgcn_mfma_f32_16x16x32_bf16(af[i], bfr[j], acc[i][j], 0, 0, 0);
        }
    }
#pragma unroll
    for (int i = 0; i < 4; ++i)
#pragma unroll
        for (int j = 0; j < 4; ++j)
#pragma unroll
            for (int r = 0; r < 4; ++r) {
                int row = m0 + wr + i * 16 + quad * 4 + r;
                int col = n0 + wc + j * 16 + ln;
                C[(size_t)row * DIM + col] = f2bf(acc[i][j][r]);
            }
}

// ---------------------------------------------------------------------------
// per (b, 64-row l-tile): S = Q K^T * scale -> softmax(mask) -> P V
// ---------------------------------------------------------------------------
__global__ __launch_bounds__(256) void attn_kernel(const u16* __restrict__ Q,
                                                   const u16* __restrict__ K,
                                                   const u16* __restrict__ Vt,
                                                   const int* __restrict__ mask,
                                                   float* __restrict__ out) {
    const int b    = blockIdx.y;
    const int l0   = blockIdx.x * 64;
    const int t    = threadIdx.x;
    const int w    = t >> 6;
    const int lane = t & 63;
    const int quad = lane >> 4;
    const int ln   = lane & 15;

    __shared__ union {
        struct { u16 q[64][64]; u16 k[128][64]; } st;   // 24 KB, gld-lds layout
        float s[64][132];                               // 33.8 KB
        u16   v[64][128];                               // 16 KB, gld-lds layout
    } uS;
    __shared__ u16   sP[64][136];
    __shared__ float sBias[128];

    const u16* Qb = Q + ((size_t)b * LQ + l0) * DIM;
    const u16* Kb = K + (size_t)b * NV * DIM;

    if (t < NV) sBias[t] = mask[b * NV + t] ? 0.0f : -1e9f;

    const int srow = lane >> 3;
    const int scol = (lane & 7) * 8;

    // ---- Phase 1: S(64x128) = Q_tile @ K_b^T ----
    f32x4 accS[4][2] = {};
    for (int ks = 0; ks < DIM / 64; ++ks) {
        __syncthreads();
#pragma unroll
        for (int p = 0; p < 2; ++p) {                   // Q: 64 rows, 16/wave
            int r = w * 16 + p * 8;
            gld16(Qb + (size_t)(r + srow) * DIM + ks * 64 + scol, &uS.st.q[r][0]);
        }
#pragma unroll
        for (int p = 0; p < 4; ++p) {                   // K: 128 rows, 32/wave
            int r = w * 32 + p * 8;
            gld16(Kb + (size_t)(r + srow) * DIM + ks * 64 + scol, &uS.st.k[r][0]);
        }
        __syncthreads();
#pragma unroll
        for (int kk = 0; kk < 2; ++kk) {
            bf16x8 af[4], bfr[2];
#pragma unroll
            for (int i = 0; i < 4; ++i) af[i]  = ld_frag(&uS.st.q[i * 16 + ln][kk * 32 + quad * 8]);
#pragma unroll
            for (int j = 0; j < 2; ++j) bfr[j] = ld_frag(&uS.st.k[w * 32 + j * 16 + ln][kk * 32 + quad * 8]);
#pragma unroll
            for (int i = 0; i < 4; ++i)
#pragma unroll
                for (int j = 0; j < 2; ++j)
                    accS[i][j] = __builtin_amdgcn_mfma_f32_16x16x32_bf16(af[i], bfr[j], accS[i][j], 0, 0, 0);
        }
    }
    __syncthreads();
    const float scale = 0.03608439182435161f;           // 768^-0.5
#pragma unroll
    for (int i = 0; i < 4; ++i)
#pragma unroll
        for (int j = 0; j < 2; ++j)
#pragma unroll
            for (int r = 0; r < 4; ++r)
                uS.s[i * 16 + quad * 4 + r][w * 32 + j * 16 + ln] = accS[i][j][r] * scale;
    __syncthreads();

    // ---- Phase 2: masked softmax over v, write P bf16 ----
    {
        const int row = t >> 2, seg = t & 3;
        float vals[32];
        float mx = -3.0e38f;
#pragma unroll
        for (int c = 0; c < 8; ++c) {
            float4 x  = *(const float4*)&uS.s[row][seg * 32 + c * 4];
            float4 bz = *(const float4*)&sBias[seg * 32 + c * 4];
            float a0 = x.x + bz.x, a1 = x.y + bz.y, a2 = x.z + bz.z, a3 = x.w + bz.w;
            vals[c * 4 + 0] = a0; vals[c * 4 + 1] = a1;
            vals[c * 4 + 2] = a2; vals[c * 4 + 3] = a3;
            mx = fmaxf(mx, fmaxf(fmaxf(a0, a1), fmaxf(a2, a3)));
        }
        mx = fmaxf(mx, __shfl_xor(mx, 1));
        mx = fmaxf(mx, __shfl_xor(mx, 2));
        float sum = 0.0f;
#pragma unroll
        for (int c = 0; c < 32; ++c) { float e = __expf(vals[c] - mx); vals[c] = e; sum += e; }
        sum += __shfl_xor(sum, 1);
        sum += __shfl_xor(sum, 2);
        const float inv = 1.0f / sum;
        __syncthreads();
#pragma unroll
        for (int c = 0; c < 4; ++c) {
            u16x8 pk;
#pragma unroll
            for (int e = 0; e < 8; ++e) pk[e] = f2bf(vals[c * 8 + e] * inv);
            *(u16x8*)&sP[row][seg * 32 + c * 8] = pk;
        }
    }
    __syncthreads();

    // ---- Phase 3: out(64x768) = P(64x128) @ V_b(128x768) ----
    const u16* Vb = Vt + (size_t)b * DIM * NV;
    float*     Ob = out + ((size_t)b * LQ + l0) * DIM;
    const int vrow = lane >> 4;                         // v-tile staging: 16 lanes/row
    const int vcol = (lane & 15) * 8;
    for (int nt = 0; nt < 12; ++nt) {
        __syncthreads();
#pragma unroll
        for (int p = 0; p < 4; ++p) {                   // 64 d-rows x 128 v, 16/wave
            int r = w * 16 + p * 4;
            gld16(Vb + (size_t)(nt * 64 + r + vrow) * NV + vcol, &uS.v[r][0]);
        }
        __syncthreads();
        f32x4 accO[4] = {};
#pragma unroll
        for (int ks = 0; ks < 4; ++ks) {
            bf16x8 af[4];
#pragma unroll
            for (int i = 0; i < 4; ++i) af[i] = ld_frag(&sP[i * 16 + ln][ks * 32 + quad * 8]);
            bf16x8 bv = ld_frag(&uS.v[w * 16 + ln][ks * 32 + quad * 8]);
#pragma unroll
            for (int i = 0; i < 4; ++i)
                accO[i] = __builtin_amdgcn_mfma_f32_16x16x32_bf16(af[i], bv, accO[i], 0, 0, 0);
        }
#pragma unroll
        for (int i = 0; i < 4; ++i)
#pragma unroll
            for (int r = 0; r < 4; ++r)
                Ob[(size_t)(i * 16 + quad * 4 + r) * DIM + nt * 64 + w * 16 + ln] = accO[i][r];
    }
}

// ---------------------------------------------------------------------------
extern "C" void kernel_launch(void* const* d_in, const int* in_sizes, int n_in,
                              void* d_out, int out_size, void* d_ws, size_t ws_size,
                              hipStream_t stream) {
    const float* lines  = (const float*)d_in[0];
    const float* videos = (const float*)d_in[1];
    const int*   mask   = (const int*)d_in[2];
    const float* w_q    = (const float*)d_in[3];
    const float* w_k    = (const float*)d_in[4];
    float*       out    = (float*)d_out;

    u16* qw  = (u16*)d_ws;                        // 16384x768 bf16 (25.2 MB)
    u16* kw  = qw  + (size_t)NB * LQ * DIM;       //  4096x768 bf16
    u16* vt  = kw  + (size_t)NB * NV * DIM;       // 32x768x128 bf16
    u16* lbf = vt  + (size_t)NB * DIM * NV;       // lines bf16
    u16* vbf = lbf + (size_t)NB * LQ * DIM;       // videos bf16
    u16* wqb = vbf + (size_t)NB * NV * DIM;       // w_q bf16
    u16* wkb = wqb + (size_t)DIM * DIM;           // w_k bf16

    cvt_kernel<<<(NB * LQ * DIM) / (256 * 8), 256, 0, stream>>>(lines,  lbf);
    cvt_kernel<<<(NB * NV * DIM) / (256 * 8), 256, 0, stream>>>(videos, vbf);
    cvt_kernel<<<(DIM * DIM)     / (256 * 8), 256, 0, stream>>>(w_q,    wqb);
    cvt_kernel<<<(DIM * DIM)     / (256 * 8), 256, 0, stream>>>(w_k,    wkb);
    vt_kernel  <<<dim3(DIM / 64, NB), 256, 0, stream>>>(videos, vt);

    proj_kernel<<<dim3(DIM / 128, (NB * LQ) / 128), 256, 0, stream>>>(lbf, wqb, qw);
    proj_kernel<<<dim3(DIM / 128, (NB * NV) / 128), 256, 0, stream>>>(vbf, wkb, kw);
    attn_kernel<<<dim3(LQ / 64, NB), 256, 0, stream>>>(qw, kw, vt, mask, out);
}

// Round 3
// 182.595 us; speedup vs baseline: 1.6497x; 1.1847x over previous
//
#include <hip/hip_runtime.h>

#define DIM 768
#define NB  32
#define LQ  512
#define NV  128

typedef unsigned short u16;
typedef unsigned int   u32;
typedef __bf16 bf16x8 __attribute__((ext_vector_type(8)));
typedef float  f32x4  __attribute__((ext_vector_type(4)));
typedef u16    u16x8  __attribute__((ext_vector_type(8)));
typedef u16    u16x4  __attribute__((ext_vector_type(4)));

typedef __attribute__((address_space(1))) const void gvoid;
typedef __attribute__((address_space(3))) void       svoid;

__device__ __forceinline__ u16 f2bf(float f) {
    u32 u = __float_as_uint(f);
    return (u16)((u + 0x7FFFu + ((u >> 16) & 1u)) >> 16);   // RNE
}

__device__ __forceinline__ bf16x8 ld_frag(const u16* p) {
    return __builtin_bit_cast(bf16x8, *(const u16x8*)p);
}

// async global->LDS, 16B/lane; LDS image = base + lane*16 (contiguous)
__device__ __forceinline__ void gld16(const void* g, void* l) {
    __builtin_amdgcn_global_load_lds((gvoid*)g, (svoid*)l, 16, 0, 0);
}

// ---------------------------------------------------------------------------
// fp32 -> bf16 streaming convert
// ---------------------------------------------------------------------------
__global__ __launch_bounds__(256) void cvt_kernel(const float* __restrict__ src,
                                                  u16* __restrict__ dst) {
    size_t i = (size_t)blockIdx.x * 256 + threadIdx.x;
    float4 a = ((const float4*)src)[i * 2];
    float4 b = ((const float4*)src)[i * 2 + 1];
    u16x8 o = { f2bf(a.x), f2bf(a.y), f2bf(a.z), f2bf(a.w),
                f2bf(b.x), f2bf(b.y), f2bf(b.z), f2bf(b.w) };
    ((u16x8*)dst)[i] = o;
}

// ---------------------------------------------------------------------------
// videos fp32 (b,v,d) -> vt2 (MFMA B-frag order for PV) + vbf row-major bf16
// vt2 frag (b,it,w,ks,lane): content V[ks*32+quad*8+e][it*128+w*16+ln]
// ---------------------------------------------------------------------------
__global__ __launch_bounds__(256) void vt_kernel(const float* __restrict__ videos,
                                                 u16* __restrict__ vt2,
                                                 u16* __restrict__ vbf) {
    const int b  = blockIdx.y;
    const int d0 = blockIdx.x * 64;
    const int t  = threadIdx.x;
    __shared__ u16 T[64][136];                      // [d_local][v]
    const float* src = videos + (size_t)b * NV * DIM;
#pragma unroll
    for (int p = 0; p < 8; ++p) {
        int f  = t + p * 256;
        int v  = f >> 4;
        int c4 = f & 15;
        float4 x = *(const float4*)(src + (size_t)v * DIM + d0 + c4 * 4);
        u16x4 o = { f2bf(x.x), f2bf(x.y), f2bf(x.z), f2bf(x.w) };
        T[c4 * 4 + 0][v] = o[0];
        T[c4 * 4 + 1][v] = o[1];
        T[c4 * 4 + 2][v] = o[2];
        T[c4 * 4 + 3][v] = o[3];
        *(u16x4*)(vbf + ((size_t)b * NV + v) * DIM + d0 + c4 * 4) = o;
    }
    __syncthreads();
#pragma unroll
    for (int p = 0; p < 4; ++p) {                   // 64 d x 16 chunks
        int f  = t + p * 256;
        int dl = f >> 4;
        int v8 = f & 15;                            // = ks*4 + quad
        int d  = d0 + dl;
        int it = d >> 7, wv = (d >> 4) & 7, lnn = d & 15;
        int ks = v8 >> 2, qd = v8 & 3;
        int lane = qd * 16 + lnn;
        size_t off = ((((size_t)b * 6 + it) * 8 + wv) * 4 + ks) * 512 + lane * 8;
        *(u16x8*)(vt2 + off) = *(const u16x8*)&T[dl][v8 * 8];
    }
}

// ---------------------------------------------------------------------------
// Fused projections: C[Mx768] = A[Mx768] @ W[768x768]^T, all bf16.
// 128x128 tile, BK=64, 8 waves, gld16 staging with XOR-swizzle.
// blockIdx.y < 128 -> Q GEMM; else K GEMM.
// ---------------------------------------------------------------------------
__global__ __launch_bounds__(512) void proj_kernel(const u16* __restrict__ A0,
                                                   const u16* __restrict__ W0,
                                                   u16* __restrict__ C0,
                                                   const u16* __restrict__ A1,
                                                   const u16* __restrict__ W1,
                                                   u16* __restrict__ C1) {
    __shared__ u16 sA[128][64];
    __shared__ u16 sB[128][64];
    const int t    = threadIdx.x;
    const int w    = t >> 6;
    const int lane = t & 63;
    const int quad = lane >> 4;
    const int ln   = lane & 15;
    const int n0   = blockIdx.x * 128;

    const u16 *A, *W; u16 *C; int m0;
    if ((int)blockIdx.y < 128) { A = A0; W = W0; C = C0; m0 = blockIdx.y * 128; }
    else                       { A = A1; W = W1; C = C1; m0 = (blockIdx.y - 128) * 128; }

    const int wr = (w >> 2) * 64;                   // 2 row-groups x 4 col-groups
    const int wc = (w & 3) * 32;
    const int srow   = lane >> 3;
    const int schunk = (lane & 7) ^ srow;           // XOR swizzle (row&7 == srow)

    f32x4 acc[4][2] = {};
#pragma unroll
    for (int ks = 0; ks < 12; ++ks) {
        __syncthreads();
#pragma unroll
        for (int p = 0; p < 2; ++p) {
            int rb = w * 16 + p * 8;
            gld16(A + (size_t)(m0 + rb + srow) * DIM + ks * 64 + schunk * 8, &sA[rb][0]);
            gld16(W + (size_t)(n0 + rb + srow) * DIM + ks * 64 + schunk * 8, &sB[rb][0]);
        }
        __syncthreads();
#pragma unroll
        for (int kk = 0; kk < 2; ++kk) {
            bf16x8 af[4], bfr[2];
#pragma unroll
            for (int i = 0; i < 4; ++i)
                af[i]  = ld_frag(&sA[wr + i * 16 + ln][((kk * 4 + quad) ^ (ln & 7)) * 8]);
#pragma unroll
            for (int j = 0; j < 2; ++j)
                bfr[j] = ld_frag(&sB[wc + j * 16 + ln][((kk * 4 + quad) ^ (ln & 7)) * 8]);
#pragma unroll
            for (int i = 0; i < 4; ++i)
#pragma unroll
                for (int j = 0; j < 2; ++j)
                    acc[i][j] = __builtin_amdgcn_mfma_f32_16x16x32_bf16(af[i], bfr[j], acc[i][j], 0, 0, 0);
        }
    }
#pragma unroll
    for (int i = 0; i < 4; ++i)
#pragma unroll
        for (int j = 0; j < 2; ++j)
#pragma unroll
            for (int r = 0; r < 4; ++r)
                C[(size_t)(m0 + wr + i * 16 + quad * 4 + r) * DIM + n0 + wc + j * 16 + ln] =
                    f2bf(acc[i][j][r]);
}

// ---------------------------------------------------------------------------
// Attention: per (b, 64 l-rows). 8 waves.
// Phase 1: S = Q K^T (dbuf'd gld16 staging, 1 barrier/iter)
// Phase 2: masked softmax (8 lanes/row)
// Phase 3: out = P V, barrier-free: P in regs, V streamed from frag-ordered vt2
// ---------------------------------------------------------------------------
__global__ __launch_bounds__(512) void attn_kernel(const u16* __restrict__ Q,
                                                   const u16* __restrict__ K,
                                                   const u16* __restrict__ Vt2,
                                                   const int* __restrict__ mask,
                                                   float* __restrict__ out) {
    const int b    = blockIdx.y;
    const int l0   = blockIdx.x * 64;
    const int t    = threadIdx.x;
    const int w    = t >> 6;
    const int lane = t & 63;
    const int quad = lane >> 4;
    const int ln   = lane & 15;

    __shared__ union {
        struct { u16 q[64][64]; u16 k[128][64]; } st;   // staging buf 0 (24 KB)
        float s[64][132];                               // scores (33.8 KB)
    } uA;
    __shared__ union {
        struct { u16 q[64][64]; u16 k[128][64]; } st;   // staging buf 1 (24 KB)
        u16 p[64][136];                                 // probs bf16 (17.4 KB)
    } uB;
    __shared__ float sBias[128];

    const u16* Qb = Q + ((size_t)b * LQ + l0) * DIM;
    const u16* Kb = K + (size_t)b * NV * DIM;
    if (t < NV) sBias[t] = mask[b * NV + t] ? 0.0f : -1e9f;

    const int srow   = lane >> 3;
    const int schunk = (lane & 7) ^ srow;

    auto stage = [&](int ks, int sel) {
        u16 (*q)[64] = sel ? uB.st.q : uA.st.q;
        u16 (*k)[64] = sel ? uB.st.k : uA.st.k;
        gld16(Qb + (size_t)(w * 8 + srow) * DIM + ks * 64 + schunk * 8, &q[w * 8][0]);
        gld16(Kb + (size_t)(w * 16 + srow) * DIM + ks * 64 + schunk * 8, &k[w * 16][0]);
        gld16(Kb + (size_t)(w * 16 + 8 + srow) * DIM + ks * 64 + schunk * 8, &k[w * 16 + 8][0]);
    };

    // ---- Phase 1: wave w computes S cols [w*16, w*16+16), rows 0..63 ----
    f32x4 accS[4] = {};
    stage(0, 0);
#pragma unroll
    for (int ks = 0; ks < 12; ++ks) {
        __syncthreads();                            // stage(ks) landed; prev reads done
        if (ks < 11) stage(ks + 1, (ks + 1) & 1);   // overlaps compute below
        u16 (*q)[64] = (ks & 1) ? uB.st.q : uA.st.q;
        u16 (*k)[64] = (ks & 1) ? uB.st.k : uA.st.k;
#pragma unroll
        for (int kk = 0; kk < 2; ++kk) {
            bf16x8 bfr = ld_frag(&k[w * 16 + ln][((kk * 4 + quad) ^ (ln & 7)) * 8]);
#pragma unroll
            for (int i = 0; i < 4; ++i) {
                bf16x8 af = ld_frag(&q[i * 16 + ln][((kk * 4 + quad) ^ (ln & 7)) * 8]);
                accS[i] = __builtin_amdgcn_mfma_f32_16x16x32_bf16(af, bfr, accS[i], 0, 0, 0);
            }
        }
    }
    __syncthreads();                                // all phase-1 LDS reads done
    const float scale = 0.03608439182435161f;       // 768^-0.5
#pragma unroll
    for (int i = 0; i < 4; ++i)
#pragma unroll
        for (int r = 0; r < 4; ++r)
            uA.s[i * 16 + quad * 4 + r][w * 16 + ln] = accS[i][r] * scale;
    __syncthreads();

    // ---- Phase 2: masked softmax, 8 lanes/row, 16 cols/lane ----
    {
        const int row = t >> 3, seg = t & 7;
        float vals[16];
        float mx = -3.0e38f;
#pragma unroll
        for (int c = 0; c < 4; ++c) {
            float4 x  = *(const float4*)&uA.s[row][seg * 16 + c * 4];
            float4 bz = *(const float4*)&sBias[seg * 16 + c * 4];
            float a0 = x.x + bz.x, a1 = x.y + bz.y, a2 = x.z + bz.z, a3 = x.w + bz.w;
            vals[c * 4 + 0] = a0; vals[c * 4 + 1] = a1;
            vals[c * 4 + 2] = a2; vals[c * 4 + 3] = a3;
            mx = fmaxf(mx, fmaxf(fmaxf(a0, a1), fmaxf(a2, a3)));
        }
        mx = fmaxf(mx, __shfl_xor(mx, 1));
        mx = fmaxf(mx, __shfl_xor(mx, 2));
        mx = fmaxf(mx, __shfl_xor(mx, 4));
        float sum = 0.0f;
#pragma unroll
        for (int c = 0; c < 16; ++c) { float e = __expf(vals[c] - mx); vals[c] = e; sum += e; }
        sum += __shfl_xor(sum, 1);
        sum += __shfl_xor(sum, 2);
        sum += __shfl_xor(sum, 4);
        const float inv = 1.0f / sum;
        __syncthreads();                            // uA.s reads done; uB.st dead
#pragma unroll
        for (int h = 0; h < 2; ++h) {
            u16x8 pk;
#pragma unroll
            for (int e = 0; e < 8; ++e) pk[e] = f2bf(vals[h * 8 + e] * inv);
            *(u16x8*)&uB.p[row][seg * 16 + h * 8] = pk;
        }
    }
    __syncthreads();                                // sP visible

    // ---- hoist P fragments into registers (A-operand layout) ----
    bf16x8 paf[4][4];
#pragma unroll
    for (int i = 0; i < 4; ++i)
#pragma unroll
        for (int ks = 0; ks < 4; ++ks)
            paf[i][ks] = ld_frag(&uB.p[i * 16 + ln][ks * 32 + quad * 8]);

    // ---- Phase 3: out = P @ V, no LDS, no barriers ----
    const u16* V2 = Vt2 + (size_t)b * 6 * 8 * 4 * 512;
    float*     Ob = out + ((size_t)b * LQ + l0) * DIM;
    for (int it = 0; it < 6; ++it) {
        f32x4 accO[4] = {};
#pragma unroll
        for (int ks = 0; ks < 4; ++ks) {
            bf16x8 bv = ld_frag(V2 + (((size_t)(it * 8 + w)) * 4 + ks) * 512 + lane * 8);
#pragma unroll
            for (int i = 0; i < 4; ++i)
                accO[i] = __builtin_amdgcn_mfma_f32_16x16x32_bf16(paf[i][ks], bv, accO[i], 0, 0, 0);
        }
#pragma unroll
        for (int i = 0; i < 4; ++i)
#pragma unroll
            for (int r = 0; r < 4; ++r)
                Ob[(size_t)(i * 16 + quad * 4 + r) * DIM + it * 128 + w * 16 + ln] = accO[i][r];
    }
}

// ---------------------------------------------------------------------------
extern "C" void kernel_launch(void* const* d_in, const int* in_sizes, int n_in,
                              void* d_out, int out_size, void* d_ws, size_t ws_size,
                              hipStream_t stream) {
    const float* lines  = (const float*)d_in[0];
    const float* videos = (const float*)d_in[1];
    const int*   mask   = (const int*)d_in[2];
    const float* w_q    = (const float*)d_in[3];
    const float* w_k    = (const float*)d_in[4];
    float*       out    = (float*)d_out;

    u16* qw  = (u16*)d_ws;                        // 16384x768
    u16* kw  = qw  + (size_t)NB * LQ * DIM;       //  4096x768
    u16* vt2 = kw  + (size_t)NB * NV * DIM;       // 32x768x128 (frag order)
    u16* lbf = vt2 + (size_t)NB * DIM * NV;       // lines bf16
    u16* vbf = lbf + (size_t)NB * LQ * DIM;       // videos bf16
    u16* wqb = vbf + (size_t)NB * NV * DIM;       // w_q bf16
    u16* wkb = wqb + (size_t)DIM * DIM;           // w_k bf16

    cvt_kernel<<<(NB * LQ * DIM) / 2048, 256, 0, stream>>>(lines, lbf);
    cvt_kernel<<<(DIM * DIM)     / 2048, 256, 0, stream>>>(w_q,   wqb);
    cvt_kernel<<<(DIM * DIM)     / 2048, 256, 0, stream>>>(w_k,   wkb);
    vt_kernel  <<<dim3(DIM / 64, NB), 256, 0, stream>>>(videos, vt2, vbf);

    proj_kernel<<<dim3(DIM / 128, 160), 512, 0, stream>>>(lbf, wqb, qw, vbf, wkb, kw);
    attn_kernel<<<dim3(LQ / 64, NB), 512, 0, stream>>>(qw, kw, vt2, mask, out);
}

// Round 4
// 168.461 us; speedup vs baseline: 1.7881x; 1.0839x over previous
//
#include <hip/hip_runtime.h>

#define DIM 768
#define NB  32
#define LQ  512
#define NV  128

typedef unsigned short u16;
typedef unsigned int   u32;
typedef __bf16 bf16x8 __attribute__((ext_vector_type(8)));
typedef float  f32x4  __attribute__((ext_vector_type(4)));
typedef u16    u16x8  __attribute__((ext_vector_type(8)));
typedef u16    u16x4  __attribute__((ext_vector_type(4)));

typedef __attribute__((address_space(1))) const void gvoid;
typedef __attribute__((address_space(3))) void       svoid;

__device__ __forceinline__ u16 f2bf(float f) {
    u32 u = __float_as_uint(f);
    return (u16)((u + 0x7FFFu + ((u >> 16) & 1u)) >> 16);   // RNE
}

__device__ __forceinline__ bf16x8 ld_frag(const u16* p) {
    return __builtin_bit_cast(bf16x8, *(const u16x8*)p);
}

__device__ __forceinline__ void gld16(const void* g, void* l) {
    __builtin_amdgcn_global_load_lds((gvoid*)g, (svoid*)l, 16, 0, 0);
}

// ---------------------------------------------------------------------------
// Fused prep: cvt(lines) | cvt(w_q) | cvt(w_k) | videos -> vt2(frag) + vbf
// block ranges: [0,6144) lines, [6144,6432) w_q, [6432,6720) w_k, [6720,7104) vt
// ---------------------------------------------------------------------------
#define NL_BLK 6144
#define NW_BLK 288

__device__ __forceinline__ void cvt_body(const float* __restrict__ src,
                                         u16* __restrict__ dst, int blk) {
    size_t i = (size_t)blk * 256 + threadIdx.x;
    float4 a = ((const float4*)src)[i * 2];
    float4 b = ((const float4*)src)[i * 2 + 1];
    u16x8 o = { f2bf(a.x), f2bf(a.y), f2bf(a.z), f2bf(a.w),
                f2bf(b.x), f2bf(b.y), f2bf(b.z), f2bf(b.w) };
    ((u16x8*)dst)[i] = o;
}

__global__ __launch_bounds__(256) void prep_kernel(const float* __restrict__ lines,
                                                   const float* __restrict__ w_q,
                                                   const float* __restrict__ w_k,
                                                   const float* __restrict__ videos,
                                                   u16* __restrict__ lbf,
                                                   u16* __restrict__ wqb,
                                                   u16* __restrict__ wkb,
                                                   u16* __restrict__ vt2,
                                                   u16* __restrict__ vbf) {
    __shared__ u16 T[64][136];
    const int bx = blockIdx.x;
    if (bx < NL_BLK)                 { cvt_body(lines, lbf, bx); return; }
    if (bx < NL_BLK + NW_BLK)        { cvt_body(w_q,   wqb, bx - NL_BLK); return; }
    if (bx < NL_BLK + 2 * NW_BLK)    { cvt_body(w_k,   wkb, bx - NL_BLK - NW_BLK); return; }

    const int v  = bx - (NL_BLK + 2 * NW_BLK);      // [0, 384)
    const int b  = v / 12;
    const int d0 = (v % 12) * 64;
    const int t  = threadIdx.x;
    const float* src = videos + (size_t)b * NV * DIM;
#pragma unroll
    for (int p = 0; p < 8; ++p) {
        int f  = t + p * 256;
        int vv = f >> 4;
        int c4 = f & 15;
        float4 x = *(const float4*)(src + (size_t)vv * DIM + d0 + c4 * 4);
        u16x4 o = { f2bf(x.x), f2bf(x.y), f2bf(x.z), f2bf(x.w) };
        T[c4 * 4 + 0][vv] = o[0];
        T[c4 * 4 + 1][vv] = o[1];
        T[c4 * 4 + 2][vv] = o[2];
        T[c4 * 4 + 3][vv] = o[3];
        *(u16x4*)(vbf + ((size_t)b * NV + vv) * DIM + d0 + c4 * 4) = o;
    }
    __syncthreads();
#pragma unroll
    for (int p = 0; p < 4; ++p) {
        int f  = t + p * 256;
        int dl = f >> 4;
        int v8 = f & 15;                            // = ks*4 + quad
        int d  = d0 + dl;
        int it = d >> 7, wv = (d >> 4) & 7, lnn = d & 15;
        int ks = v8 >> 2, qd = v8 & 3;
        int lane = qd * 16 + lnn;
        size_t off = ((((size_t)b * 6 + it) * 8 + wv) * 4 + ks) * 512 + lane * 8;
        *(u16x8*)(vt2 + off) = *(const u16x8*)&T[dl][v8 * 8];
    }
}

// ---------------------------------------------------------------------------
// Fused projections, XCD-swizzled 1-D grid (960 blocks):
//   i < 768: Q GEMM (128 m-tiles x 6 n);  i >= 768: K GEMM (32 m-tiles x 6 n)
// Within each region: xcd = i%8; the 6 n-tiles of one m-tile are consecutive
// slots on one XCD -> A-tile L2-resident across its 6 uses.
// ---------------------------------------------------------------------------
__global__ __launch_bounds__(512) void proj_kernel(const u16* __restrict__ A0,
                                                   const u16* __restrict__ W0,
                                                   u16* __restrict__ C0,
                                                   const u16* __restrict__ A1,
                                                   const u16* __restrict__ W1,
                                                   u16* __restrict__ C1) {
    __shared__ u16 sA[128][64];
    __shared__ u16 sB[128][64];
    const int t    = threadIdx.x;
    const int w    = t >> 6;
    const int lane = t & 63;
    const int quad = lane >> 4;
    const int ln   = lane & 15;

    const u16 *A, *W; u16 *C; int m0, n0;
    {
        int i = blockIdx.x;
        if (i < 768) { A = A0; W = W0; C = C0; }
        else         { A = A1; W = W1; C = C1; i -= 768; }
        int xcd = i & 7, s = i >> 3;
        m0 = ((s / 6) * 8 + xcd) * 128;
        n0 = (s % 6) * 128;
    }

    const int wr = (w >> 2) * 64;
    const int wc = (w & 3) * 32;
    const int srow   = lane >> 3;
    const int schunk = (lane & 7) ^ srow;           // XOR swizzle

    f32x4 acc[4][2] = {};
#pragma unroll
    for (int ks = 0; ks < 12; ++ks) {
        __syncthreads();
#pragma unroll
        for (int p = 0; p < 2; ++p) {
            int rb = w * 16 + p * 8;
            gld16(A + (size_t)(m0 + rb + srow) * DIM + ks * 64 + schunk * 8, &sA[rb][0]);
            gld16(W + (size_t)(n0 + rb + srow) * DIM + ks * 64 + schunk * 8, &sB[rb][0]);
        }
        __syncthreads();
#pragma unroll
        for (int kk = 0; kk < 2; ++kk) {
            bf16x8 af[4], bfr[2];
#pragma unroll
            for (int i = 0; i < 4; ++i)
                af[i]  = ld_frag(&sA[wr + i * 16 + ln][((kk * 4 + quad) ^ (ln & 7)) * 8]);
#pragma unroll
            for (int j = 0; j < 2; ++j)
                bfr[j] = ld_frag(&sB[wc + j * 16 + ln][((kk * 4 + quad) ^ (ln & 7)) * 8]);
#pragma unroll
            for (int i = 0; i < 4; ++i)
#pragma unroll
                for (int j = 0; j < 2; ++j)
                    acc[i][j] = __builtin_amdgcn_mfma_f32_16x16x32_bf16(af[i], bfr[j], acc[i][j], 0, 0, 0);
        }
    }
#pragma unroll
    for (int i = 0; i < 4; ++i)
#pragma unroll
        for (int j = 0; j < 2; ++j)
#pragma unroll
            for (int r = 0; r < 4; ++r)
                C[(size_t)(m0 + wr + i * 16 + quad * 4 + r) * DIM + n0 + wc + j * 16 + ln] =
                    f2bf(acc[i][j][r]);
}

// ---------------------------------------------------------------------------
// Attention, XCD-swizzled 1-D grid (256 blocks): 8 l-tiles of one batch land
// on one XCD -> K/V2 fetched once per XCD instead of 8x.
// ---------------------------------------------------------------------------
__global__ __launch_bounds__(512) void attn_kernel(const u16* __restrict__ Q,
                                                   const u16* __restrict__ K,
                                                   const u16* __restrict__ Vt2,
                                                   const int* __restrict__ mask,
                                                   float* __restrict__ out) {
    int b, l0;
    {
        int i = blockIdx.x;
        int xcd = i & 7, s = i >> 3;
        b  = (s >> 3) * 8 + xcd;
        l0 = (s & 7) * 64;
    }
    const int t    = threadIdx.x;
    const int w    = t >> 6;
    const int lane = t & 63;
    const int quad = lane >> 4;
    const int ln   = lane & 15;

    __shared__ union {
        struct { u16 q[64][64]; u16 k[128][64]; } st;
        float s[64][132];
    } uA;
    __shared__ union {
        struct { u16 q[64][64]; u16 k[128][64]; } st;
        u16 p[64][136];
    } uB;
    __shared__ float sBias[128];

    const u16* Qb = Q + ((size_t)b * LQ + l0) * DIM;
    const u16* Kb = K + (size_t)b * NV * DIM;
    if (t < NV) sBias[t] = mask[b * NV + t] ? 0.0f : -1e9f;

    const int srow   = lane >> 3;
    const int schunk = (lane & 7) ^ srow;

    auto stage = [&](int ks, int sel) {
        u16 (*q)[64] = sel ? uB.st.q : uA.st.q;
        u16 (*k)[64] = sel ? uB.st.k : uA.st.k;
        gld16(Qb + (size_t)(w * 8 + srow) * DIM + ks * 64 + schunk * 8, &q[w * 8][0]);
        gld16(Kb + (size_t)(w * 16 + srow) * DIM + ks * 64 + schunk * 8, &k[w * 16][0]);
        gld16(Kb + (size_t)(w * 16 + 8 + srow) * DIM + ks * 64 + schunk * 8, &k[w * 16 + 8][0]);
    };

    // ---- Phase 1: S = Q K^T ----
    f32x4 accS[4] = {};
    stage(0, 0);
#pragma unroll
    for (int ks = 0; ks < 12; ++ks) {
        __syncthreads();
        if (ks < 11) stage(ks + 1, (ks + 1) & 1);
        u16 (*q)[64] = (ks & 1) ? uB.st.q : uA.st.q;
        u16 (*k)[64] = (ks & 1) ? uB.st.k : uA.st.k;
#pragma unroll
        for (int kk = 0; kk < 2; ++kk) {
            bf16x8 bfr = ld_frag(&k[w * 16 + ln][((kk * 4 + quad) ^ (ln & 7)) * 8]);
#pragma unroll
            for (int i = 0; i < 4; ++i) {
                bf16x8 af = ld_frag(&q[i * 16 + ln][((kk * 4 + quad) ^ (ln & 7)) * 8]);
                accS[i] = __builtin_amdgcn_mfma_f32_16x16x32_bf16(af, bfr, accS[i], 0, 0, 0);
            }
        }
    }
    __syncthreads();
    const float scale = 0.03608439182435161f;       // 768^-0.5
#pragma unroll
    for (int i = 0; i < 4; ++i)
#pragma unroll
        for (int r = 0; r < 4; ++r)
            uA.s[i * 16 + quad * 4 + r][w * 16 + ln] = accS[i][r] * scale;
    __syncthreads();

    // ---- Phase 2: masked softmax ----
    {
        const int row = t >> 3, seg = t & 7;
        float vals[16];
        float mx = -3.0e38f;
#pragma unroll
        for (int c = 0; c < 4; ++c) {
            float4 x  = *(const float4*)&uA.s[row][seg * 16 + c * 4];
            float4 bz = *(const float4*)&sBias[seg * 16 + c * 4];
            float a0 = x.x + bz.x, a1 = x.y + bz.y, a2 = x.z + bz.z, a3 = x.w + bz.w;
            vals[c * 4 + 0] = a0; vals[c * 4 + 1] = a1;
            vals[c * 4 + 2] = a2; vals[c * 4 + 3] = a3;
            mx = fmaxf(mx, fmaxf(fmaxf(a0, a1), fmaxf(a2, a3)));
        }
        mx = fmaxf(mx, __shfl_xor(mx, 1));
        mx = fmaxf(mx, __shfl_xor(mx, 2));
        mx = fmaxf(mx, __shfl_xor(mx, 4));
        float sum = 0.0f;
#pragma unroll
        for (int c = 0; c < 16; ++c) { float e = __expf(vals[c] - mx); vals[c] = e; sum += e; }
        sum += __shfl_xor(sum, 1);
        sum += __shfl_xor(sum, 2);
        sum += __shfl_xor(sum, 4);
        const float inv = 1.0f / sum;
        __syncthreads();
#pragma unroll
        for (int h = 0; h < 2; ++h) {
            u16x8 pk;
#pragma unroll
            for (int e = 0; e < 8; ++e) pk[e] = f2bf(vals[h * 8 + e] * inv);
            *(u16x8*)&uB.p[row][seg * 16 + h * 8] = pk;
        }
    }
    __syncthreads();

    bf16x8 paf[4][4];
#pragma unroll
    for (int i = 0; i < 4; ++i)
#pragma unroll
        for (int ks = 0; ks < 4; ++ks)
            paf[i][ks] = ld_frag(&uB.p[i * 16 + ln][ks * 32 + quad * 8]);

    // ---- Phase 3: out = P @ V, no LDS, no barriers ----
    const u16* V2 = Vt2 + (size_t)b * 6 * 8 * 4 * 512;
    float*     Ob = out + ((size_t)b * LQ + l0) * DIM;
    for (int it = 0; it < 6; ++it) {
        f32x4 accO[4] = {};
#pragma unroll
        for (int ks = 0; ks < 4; ++ks) {
            bf16x8 bv = ld_frag(V2 + (((size_t)(it * 8 + w)) * 4 + ks) * 512 + lane * 8);
#pragma unroll
            for (int i = 0; i < 4; ++i)
                accO[i] = __builtin_amdgcn_mfma_f32_16x16x32_bf16(paf[i][ks], bv, accO[i], 0, 0, 0);
        }
#pragma unroll
        for (int i = 0; i < 4; ++i)
#pragma unroll
            for (int r = 0; r < 4; ++r)
                Ob[(size_t)(i * 16 + quad * 4 + r) * DIM + it * 128 + w * 16 + ln] = accO[i][r];
    }
}

// ---------------------------------------------------------------------------
extern "C" void kernel_launch(void* const* d_in, const int* in_sizes, int n_in,
                              void* d_out, int out_size, void* d_ws, size_t ws_size,
                              hipStream_t stream) {
    const float* lines  = (const float*)d_in[0];
    const float* videos = (const float*)d_in[1];
    const int*   mask   = (const int*)d_in[2];
    const float* w_q    = (const float*)d_in[3];
    const float* w_k    = (const float*)d_in[4];
    float*       out    = (float*)d_out;

    u16* qw  = (u16*)d_ws;                        // 16384x768
    u16* kw  = qw  + (size_t)NB * LQ * DIM;       //  4096x768
    u16* vt2 = kw  + (size_t)NB * NV * DIM;       // 32x768x128 (frag order)
    u16* lbf = vt2 + (size_t)NB * DIM * NV;       // lines bf16
    u16* vbf = lbf + (size_t)NB * LQ * DIM;       // videos bf16
    u16* wqb = vbf + (size_t)NB * NV * DIM;       // w_q bf16
    u16* wkb = wqb + (size_t)DIM * DIM;           // w_k bf16

    prep_kernel<<<NL_BLK + 2 * NW_BLK + 384, 256, 0, stream>>>(
        lines, w_q, w_k, videos, lbf, wqb, wkb, vt2, vbf);
    proj_kernel<<<960, 512, 0, stream>>>(lbf, wqb, qw, vbf, wkb, kw);
    attn_kernel<<<256, 512, 0, stream>>>(qw, kw, vt2, mask, out);
}